// Round 11
// baseline (343.022 us; speedup 1.0000x reference)
//
#include <hip/hip_runtime.h>
#include <math.h>

// spe_self_atten: out[b] = softmax( (Xb Xb^T) / max(n_i n_j, eps) ) Xb + Xb
// B=256, C=200, L=1024. f32 in/out, bf16 MFMA internally. Residual via P += I.
// Round 11: round-10 base + T4-lite. hipcc __syncthreads() drains vmcnt(0) at
// every barrier, killing load prefetch. All inter-wave communication here is
// LDS-only, so barriers become {s_waitcnt lgkmcnt(0); s_barrier} -- global
// loads stay in flight across barriers. Pipeline deepened to 2 register sets
// in both phases; phase-2 chunk-0/1 loads issue before softmax.

typedef unsigned int uint32;
typedef __attribute__((ext_vector_type(8))) short bf16x8;   // 8 bf16 (4 VGPRs)
typedef __attribute__((ext_vector_type(4))) float f32x4;    // MFMA accum

#define CC 200
#define LL 1024
#define EPSV 1e-8f
#define PLSTR 116   // P row stride (dw)
#define XASTR 36    // phase-1 slab row stride (dw), == 4 mod 32
#define TSTR 116    // phase-2 chunk col stride (dw)

__device__ __forceinline__ uint32 bfb(float f) {
  // f32 -> bf16 bits, round-to-nearest-even
  uint32 u = __float_as_uint(f);
  u += 0x7fffu + ((u >> 16) & 1u);
  return u >> 16;
}

// LDS-only barrier: drain LDS ops (producer writes visible), raw s_barrier,
// compiler memory fences on both sides. Global loads stay in flight (the
// whole point -- __syncthreads would s_waitcnt vmcnt(0) and kill prefetch).
__device__ __forceinline__ void barrier_lds() {
  asm volatile("s_waitcnt lgkmcnt(0)" ::: "memory");
  __builtin_amdgcn_s_barrier();
  asm volatile("" ::: "memory");
}

// ---- phase-1 staging: 3200 float4; thread covers idx = tid + i*512 ---------
#define P1_LOAD(dst, s_) do {                                              \
    _Pragma("unroll")                                                      \
    for (int i = 0; i < 7; ++i) {                                          \
      int idx = tid + i * 512;                                             \
      if (idx < 3200) {                                                    \
        int row = idx >> 4, c4 = idx & 15;                                 \
        dst[i] = *(const float4*)(xb + row * LL + (s_) * 64 + c4 * 4);     \
      }                                                                    \
    }                                                                      \
  } while (0)

#define P1_WRITE(buf_, src) do {                                           \
    _Pragma("unroll")                                                      \
    for (int i = 0; i < 7; ++i) {                                          \
      int idx = tid + i * 512;                                             \
      if (idx < 3200) {                                                    \
        int row = idx >> 4, c4 = idx & 15;                                 \
        uint2 wv_;                                                         \
        wv_.x = bfb(src[i].x) | (bfb(src[i].y) << 16);                     \
        wv_.y = bfb(src[i].z) | (bfb(src[i].w) << 16);                     \
        *(uint2*)&(buf_)[row * XASTR + c4 * 2] = wv_;                      \
      }                                                                    \
    }                                                                      \
  } while (0)

// ---- phase-2 staging: thread (w,lane): col=lane, kpp=p*8+w, rows 4kpp..+3 --
#define P2_LOAD(dst, n_) do {                                              \
    _Pragma("unroll")                                                      \
    for (int p = 0; p < 7; ++p) {                                          \
      int rb4 = (p * 8 + w) * 4;                                           \
      _Pragma("unroll")                                                    \
      for (int q = 0; q < 4; ++q) {                                        \
        int r = rb4 + q;                                                   \
        dst[p][q] = (r < CC) ? xb[r * LL + (n_) + lane] : 0.f;             \
      }                                                                    \
    }                                                                      \
  } while (0)

#define P2_WRITE(buf_, src) do {                                           \
    _Pragma("unroll")                                                      \
    for (int p = 0; p < 7; ++p) {                                          \
      int kpp = p * 8 + w;                                                 \
      uint2 wv_;                                                           \
      wv_.x = bfb(src[p][0]) | (bfb(src[p][1]) << 16);                     \
      wv_.y = bfb(src[p][2]) | (bfb(src[p][3]) << 16);                     \
      *(uint2*)&(buf_)[lane * TSTR + 2 * (kpp ^ swz)] = wv_;               \
    }                                                                      \
  } while (0)

__global__ __launch_bounds__(512, 1)
void spe_attn_kernel(const float* __restrict__ x, float* __restrict__ out) {
  const int tid  = threadIdx.x;
  const int lane = tid & 63;
  const int w    = tid >> 6;       // wave 0..7
  const int lm   = lane & 15;
  const int lg   = lane >> 4;
  const int bidx = blockIdx.x;
  const float* xb = x + (size_t)bidx * (CC * LL);
  float* ob       = out + (size_t)bidx * (CC * LL);

  // LDS layout (dwords), total 39312 dw = 157,248 B:
  //  pl    [0,24128)      : P bf16, 208 rows x 232 cols (116 dw stride)
  //  xa0   [24128,31616)  : phase-1 slab buf A, 208 rows x 72 bf16 (36 dw)
  //  xa1   [31616,39104)  : phase-1 slab buf B
  //  xbf0/1 (alias xa0/xa1): phase-2 ping-pong chunk, col-major 64 x 116 dw
  //  norms [39104,39312)  : 208 floats
  __shared__ uint32 LDS[39312];
  uint32* pl    = LDS;
  uint32* xa0   = LDS + 24128;
  uint32* xa1   = LDS + 31616;
  uint32* xbf0  = LDS + 24128;
  uint32* xbf1  = LDS + 31616;
  float*  norms = (float*)(LDS + 39104);

  const bool two = (w < 5);            // waves 0..4 own row-tiles {w, w+8}
  const int rb0 = w;
  const int rb1 = two ? (w + 8) : w;

  // ---------------- Phase 1: Gram S = Xb Xb^T, 2-deep pipeline ---------------
  const f32x4 fz = {0.f, 0.f, 0.f, 0.f};
  f32x4 acc[2][13];
  #pragma unroll
  for (int i = 0; i < 2; ++i)
    #pragma unroll
    for (int j = 0; j < 13; ++j) acc[i][j] = fz;

  // zero pad rows 200..207 of both slab buffers
  if (tid < 288) { xa0[7200 + tid] = 0u; xa1[7200 + tid] = 0u; }

  // slab k lives in set: k even -> A, k odd -> B
  float4 vstA[7], vstB[7];
  P1_LOAD(vstA, 0);                    // issue slab 0
  P1_LOAD(vstB, 1);                    // issue slab 1 (both in flight)
  P1_WRITE(xa0, vstA);                 // waits slab-0 loads only
  P1_LOAD(vstA, 2);                    // issue slab 2

  for (int s = 0; s < 16; ++s) {
    barrier_lds();                     // slab s visible; loads stay in flight
    const uint32* cur = (s & 1) ? xa1 : xa0;
    __builtin_amdgcn_s_setprio(1);
    #pragma unroll
    for (int ks = 0; ks < 2; ++ks) {
      bf16x8 a0 = *(const bf16x8*)&cur[(rb0 * 16 + lm) * XASTR + ks * 16 + lg * 4];
      bf16x8 a1 = a0;
      if (two) a1 = *(const bf16x8*)&cur[(rb1 * 16 + lm) * XASTR + ks * 16 + lg * 4];
      #pragma unroll
      for (int ct = 0; ct < 13; ++ct) {
        bf16x8 bf = *(const bf16x8*)&cur[(ct * 16 + lm) * XASTR + ks * 16 + lg * 4];
        acc[0][ct] = __builtin_amdgcn_mfma_f32_16x16x32_bf16(a0, bf, acc[0][ct], 0, 0, 0);
        if (two)
          acc[1][ct] = __builtin_amdgcn_mfma_f32_16x16x32_bf16(a1, bf, acc[1][ct], 0, 0, 0);
      }
    }
    __builtin_amdgcn_s_setprio(0);
    if (s + 1 < 16) {                  // write slab s+1 (loads issued 2 iters ago)
      uint32* nxt = (s & 1) ? xa0 : xa1;
      if (s & 1) { P1_WRITE(nxt, vstA); } else { P1_WRITE(nxt, vstB); }
    }
    if (s + 3 < 16) {                  // reissue freed set with slab s+3
      if (s & 1) { P1_LOAD(vstA, s + 3); } else { P1_LOAD(vstB, s + 3); }
    }
  }

  // ------ phase-2 chunk-0/1 loads: issue NOW, hide under norms + softmax -----
  float pv0[7][4], pv1[7][4];
  const int swz = ((lane >> 3) & 3) << 1;
  P2_LOAD(pv0, 0);
  P2_LOAD(pv1, 64);

  // ---------------- norms from Gram diagonal (round-10 verbatim) -------------
  #pragma unroll
  for (int rbi = 0; rbi < 2; ++rbi) {
    if (rbi == 0 || two) {
      int rb = rbi ? rb1 : rb0;
      #pragma unroll
      for (int ct = 0; ct < 13; ++ct) {
        if (ct == rb) {
          #pragma unroll
          for (int r = 0; r < 4; ++r) {
            int ri = lg * 4 + r;
            if (lm == ri) norms[rb * 16 + ri] = sqrtf(acc[rbi][ct][r]);
          }
        }
      }
    }
  }
  barrier_lds();                       // norms visible; chunk loads in flight

  // ---------------- softmax rows + (P+I) -> LDS bf16 (round-10 verbatim) -----
  float cn[13];
  #pragma unroll
  for (int ct = 0; ct < 13; ++ct) cn[ct] = norms[ct * 16 + lm];

  #pragma unroll
  for (int rbi = 0; rbi < 2; ++rbi) {
    if (rbi == 0 || two) {
      int rb = rbi ? rb1 : rb0;
      #pragma unroll
      for (int r = 0; r < 4; ++r) {
        int grow = rb * 16 + lg * 4 + r;
        float rn = norms[grow];
        float sv[13];
        float m = -INFINITY;
        #pragma unroll
        for (int ct = 0; ct < 13; ++ct) {
          int gc = ct * 16 + lm;
          float sval = acc[rbi][ct][r] / fmaxf(rn * cn[ct], EPSV);
          sval = (gc < CC) ? sval : -INFINITY;
          sv[ct] = sval;
          m = fmaxf(m, sval);
        }
        #pragma unroll
        for (int off = 1; off < 16; off <<= 1) m = fmaxf(m, __shfl_xor(m, off));
        float sum = 0.f;
        #pragma unroll
        for (int ct = 0; ct < 13; ++ct) {
          float e = __expf(sv[ct] - m);
          sv[ct] = e;
          sum += e;
        }
        #pragma unroll
        for (int off = 1; off < 16; off <<= 1) sum += __shfl_xor(sum, off);
        float inv = 1.0f / sum;
        #pragma unroll
        for (int ct = 0; ct < 13; ++ct) {
          int gc = ct * 16 + lm;
          float p = sv[ct] * inv + ((gc == grow) ? 1.0f : 0.0f);   // P += I
          uint32 pb = bfb(p);
          uint32 qb = (uint32)__shfl_xor((int)pb, 1);
          if (!(lane & 1)) pl[grow * PLSTR + ct * 8 + (lm >> 1)] = pb | (qb << 16);
        }
      }
      // zero P cols 200..223 (dw 100..111) for this row-block
      for (int i = lane; i < 256; i += 64) {
        int rr = i >> 4, c = i & 15;
        if (c < 12) pl[(rb * 16 + rr) * PLSTR + 100 + c] = 0u;
      }
    }
  }

  // stage chunk 0 (xa0 region dead since norms barrier), reissue set with C2
  P2_WRITE(xbf0, pv0);
  P2_LOAD(pv0, 128);

  // A-fragments (own rows only; this wave wrote them -> intra-wave, no barrier)
  bf16x8 pa[2][7];
  #pragma unroll
  for (int ks = 0; ks < 7; ++ks) {
    pa[0][ks] = *(const bf16x8*)&pl[(rb0 * 16 + lm) * PLSTR + ks * 16 + lg * 4];
    if (two)
      pa[1][ks] = *(const bf16x8*)&pl[(rb1 * 16 + lm) * PLSTR + ks * 16 + lg * 4];
  }

  // ---------------- Phase 2: out = (P+I) @ Xb, 16 chunks, 2-deep -------------
  // chunk k lives in pv[k&1]; write chunk nc+1 at iter nc; issue chunk nc+3.
  for (int nc = 0; nc < 16; ++nc) {
    const int n0 = nc * 64;
    barrier_lds();                     // chunk nc staged; loads stay in flight

    const uint32* XC = (nc & 1) ? xbf1 : xbf0;
    f32x4 acc2[2][4];
    #pragma unroll
    for (int i = 0; i < 2; ++i)
      #pragma unroll
      for (int j = 0; j < 4; ++j) acc2[i][j] = fz;

    __builtin_amdgcn_s_setprio(1);
    #pragma unroll
    for (int ks = 0; ks < 7; ++ks) {   // K = 224 (P cols 200..223 zero)
      #pragma unroll
      for (int ct = 0; ct < 4; ++ct) {
        int col = ct * 16 + lm;
        int s2 = ((col >> 3) & 3) << 1;
        bf16x8 b = *(const bf16x8*)&XC[col * TSTR + 2 * ((ks * 8 + lg * 2) ^ s2)];
        acc2[0][ct] = __builtin_amdgcn_mfma_f32_16x16x32_bf16(pa[0][ks], b, acc2[0][ct], 0, 0, 0);
        if (two)
          acc2[1][ct] = __builtin_amdgcn_mfma_f32_16x16x32_bf16(pa[1][ks], b, acc2[1][ct], 0, 0, 0);
      }
    }
    __builtin_amdgcn_s_setprio(0);

    if (nc + 1 < 16) {                 // stage chunk nc+1 (loads ~2 iters old)
      uint32* XN = (nc & 1) ? xbf0 : xbf1;
      if (nc & 1) { P2_WRITE(XN, pv0); } else { P2_WRITE(XN, pv1); }
    }
    if (nc + 3 < 16) {                 // reissue freed set with chunk nc+3
      if (nc & 1) { P2_LOAD(pv0, (nc + 3) * 64); } else { P2_LOAD(pv1, (nc + 3) * 64); }
    }

    #pragma unroll
    for (int rbi = 0; rbi < 2; ++rbi) {
      if (rbi == 0 || two) {
        int rb = rbi ? rb1 : rb0;
        #pragma unroll
        for (int ct = 0; ct < 4; ++ct) {
          #pragma unroll
          for (int r = 0; r < 4; ++r) {
            int grow = rb * 16 + lg * 4 + r;
            if (grow < CC) ob[grow * LL + n0 + ct * 16 + lm] = acc2[rbi][ct][r];
          }
        }
      }
    }
  }
}

extern "C" void kernel_launch(void* const* d_in, const int* in_sizes, int n_in,
                              void* d_out, int out_size, void* d_ws, size_t ws_size,
                              hipStream_t stream) {
  const float* x = (const float*)d_in[0];
  float* out = (float*)d_out;
  const int B = in_sizes[0] / (CC * LL);   // 256
  spe_attn_kernel<<<dim3(B), dim3(512), 0, stream>>>(x, out);
}

// Round 12
// 156.300 us; speedup vs baseline: 2.1946x; 2.1946x over previous
//
#include <hip/hip_runtime.h>
#include <math.h>

// spe_self_atten: out[b] = softmax( (Xb Xb^T) / max(n_i n_j, eps) ) Xb + Xb
// B=256, C=200, L=1024. f32 in/out, bf16 MFMA internally. Residual via P += I.
// Round 12: round-10 base; ONLY phase-1 changed to a register-budgeted 2-deep
// prefetch (vstA/vstB) with lgkm-only barriers so slab loads stay in flight
// across barriers (compiler emits counted vmcnt at the LDS write instead of a
// forced vmcnt(0) drain). No pv preload before softmax (r11's spill source).
// __launch_bounds__(512,2) caps unified regs at 256 (peak liveness ~190).

typedef unsigned int uint32;
typedef __attribute__((ext_vector_type(8))) short bf16x8;   // 8 bf16 (4 VGPRs)
typedef __attribute__((ext_vector_type(4))) float f32x4;    // MFMA accum

#define CC 200
#define LL 1024
#define EPSV 1e-8f
#define PLSTR 116   // P row stride (dw)
#define XASTR 36    // phase-1 slab row stride (dw), == 4 mod 32
#define TSTR 116    // phase-2 chunk col stride (dw)

__device__ __forceinline__ uint32 bfb(float f) {
  // f32 -> bf16 bits, round-to-nearest-even
  uint32 u = __float_as_uint(f);
  u += 0x7fffu + ((u >> 16) & 1u);
  return u >> 16;
}

// LDS-only barrier: drain LDS ops (producer writes visible), raw s_barrier.
// Global loads stay in flight (__syncthreads would force vmcnt(0)).
__device__ __forceinline__ void barrier_lds() {
  asm volatile("s_waitcnt lgkmcnt(0)" ::: "memory");
  __builtin_amdgcn_s_barrier();
  asm volatile("" ::: "memory");
}

// ---- phase-1 staging: 3200 float4; thread covers idx = tid + i*512 ---------
#define P1_LOAD(dst, s_) do {                                              \
    _Pragma("unroll")                                                      \
    for (int i = 0; i < 7; ++i) {                                          \
      int idx = tid + i * 512;                                             \
      if (idx < 3200) {                                                    \
        int row = idx >> 4, c4 = idx & 15;                                 \
        dst[i] = *(const float4*)(xb + row * LL + (s_) * 64 + c4 * 4);     \
      }                                                                    \
    }                                                                      \
  } while (0)

#define P1_WRITE(buf_, src) do {                                           \
    _Pragma("unroll")                                                      \
    for (int i = 0; i < 7; ++i) {                                          \
      int idx = tid + i * 512;                                             \
      if (idx < 3200) {                                                    \
        int row = idx >> 4, c4 = idx & 15;                                 \
        uint2 wv_;                                                         \
        wv_.x = bfb(src[i].x) | (bfb(src[i].y) << 16);                     \
        wv_.y = bfb(src[i].z) | (bfb(src[i].w) << 16);                     \
        *(uint2*)&(buf_)[row * XASTR + c4 * 2] = wv_;                      \
      }                                                                    \
    }                                                                      \
  } while (0)

__global__ __launch_bounds__(512, 2)
void spe_attn_kernel(const float* __restrict__ x, float* __restrict__ out) {
  const int tid  = threadIdx.x;
  const int lane = tid & 63;
  const int w    = tid >> 6;       // wave 0..7
  const int lm   = lane & 15;
  const int lg   = lane >> 4;
  const int bidx = blockIdx.x;
  const float* xb = x + (size_t)bidx * (CC * LL);
  float* ob       = out + (size_t)bidx * (CC * LL);

  // LDS layout (dwords), total 39312 dw = 157,248 B:
  //  pl    [0,24128)      : P bf16, 208 rows x 232 cols (116 dw stride)
  //  xa0   [24128,31616)  : phase-1 slab buf A, 208 rows x 72 bf16 (36 dw)
  //  xa1   [31616,39104)  : phase-1 slab buf B
  //  xbf0/1 (alias xa0/xa1): phase-2 ping-pong chunk, col-major 64 x 116 dw
  //  norms [39104,39312)  : 208 floats
  __shared__ uint32 LDS[39312];
  uint32* pl    = LDS;
  uint32* xa0   = LDS + 24128;
  uint32* xa1   = LDS + 31616;
  uint32* xbf0  = LDS + 24128;
  uint32* xbf1  = LDS + 31616;
  float*  norms = (float*)(LDS + 39104);

  const bool two = (w < 5);            // waves 0..4 own row-tiles {w, w+8}
  const int rb0 = w;
  const int rb1 = two ? (w + 8) : w;

  // ---------------- Phase 1: Gram S = Xb Xb^T, 2-deep prefetch ---------------
  const f32x4 fz = {0.f, 0.f, 0.f, 0.f};
  f32x4 acc[2][13];
  #pragma unroll
  for (int i = 0; i < 2; ++i)
    #pragma unroll
    for (int j = 0; j < 13; ++j) acc[i][j] = fz;

  // zero pad rows 200..207 of both slab buffers
  if (tid < 288) { xa0[7200 + tid] = 0u; xa1[7200 + tid] = 0u; }

  // slab k lives in set: k even -> A, k odd -> B
  float4 vstA[7], vstB[7];
  P1_LOAD(vstA, 0);                    // issue slab 0
  P1_LOAD(vstB, 1);                    // issue slab 1 (stays in flight)
  P1_WRITE(xa0, vstA);                 // waits slab-0 loads only (vmcnt(7))
  P1_LOAD(vstA, 2);                    // issue slab 2

  for (int s = 0; s < 16; ++s) {
    barrier_lds();                     // slab s visible; loads stay in flight
    const uint32* cur = (s & 1) ? xa1 : xa0;
    __builtin_amdgcn_s_setprio(1);
    #pragma unroll
    for (int ks = 0; ks < 2; ++ks) {
      bf16x8 a0 = *(const bf16x8*)&cur[(rb0 * 16 + lm) * XASTR + ks * 16 + lg * 4];
      bf16x8 a1 = a0;
      if (two) a1 = *(const bf16x8*)&cur[(rb1 * 16 + lm) * XASTR + ks * 16 + lg * 4];
      #pragma unroll
      for (int ct = 0; ct < 13; ++ct) {
        bf16x8 bf = *(const bf16x8*)&cur[(ct * 16 + lm) * XASTR + ks * 16 + lg * 4];
        acc[0][ct] = __builtin_amdgcn_mfma_f32_16x16x32_bf16(a0, bf, acc[0][ct], 0, 0, 0);
        if (two)
          acc[1][ct] = __builtin_amdgcn_mfma_f32_16x16x32_bf16(a1, bf, acc[1][ct], 0, 0, 0);
      }
    }
    __builtin_amdgcn_s_setprio(0);
    if (s + 1 < 16) {                  // write slab s+1 (loads issued 2 iters ago)
      uint32* nxt = (s & 1) ? xa0 : xa1;
      if (s & 1) { P1_WRITE(nxt, vstA); } else { P1_WRITE(nxt, vstB); }
    }
    if (s + 3 < 16) {                  // reissue freed set with slab s+3
      if (s & 1) { P1_LOAD(vstA, s + 3); } else { P1_LOAD(vstB, s + 3); }
    }
  }

  // ---------------- norms from Gram diagonal (round-10 verbatim) -------------
  #pragma unroll
  for (int rbi = 0; rbi < 2; ++rbi) {
    if (rbi == 0 || two) {
      int rb = rbi ? rb1 : rb0;
      #pragma unroll
      for (int ct = 0; ct < 13; ++ct) {
        if (ct == rb) {
          #pragma unroll
          for (int r = 0; r < 4; ++r) {
            int ri = lg * 4 + r;
            if (lm == ri) norms[rb * 16 + ri] = sqrtf(acc[rbi][ct][r]);
          }
        }
      }
    }
  }
  barrier_lds();                       // norms visible (no global loads in flight)

  // ---------------- softmax rows + (P+I) -> LDS bf16 (round-10 verbatim) -----
  float cn[13];
  #pragma unroll
  for (int ct = 0; ct < 13; ++ct) cn[ct] = norms[ct * 16 + lm];

  #pragma unroll
  for (int rbi = 0; rbi < 2; ++rbi) {
    if (rbi == 0 || two) {
      int rb = rbi ? rb1 : rb0;
      #pragma unroll
      for (int r = 0; r < 4; ++r) {
        int grow = rb * 16 + lg * 4 + r;
        float rn = norms[grow];
        float sv[13];
        float m = -INFINITY;
        #pragma unroll
        for (int ct = 0; ct < 13; ++ct) {
          int gc = ct * 16 + lm;
          float sval = acc[rbi][ct][r] / fmaxf(rn * cn[ct], EPSV);
          sval = (gc < CC) ? sval : -INFINITY;
          sv[ct] = sval;
          m = fmaxf(m, sval);
        }
        #pragma unroll
        for (int off = 1; off < 16; off <<= 1) m = fmaxf(m, __shfl_xor(m, off));
        float sum = 0.f;
        #pragma unroll
        for (int ct = 0; ct < 13; ++ct) {
          float e = __expf(sv[ct] - m);
          sv[ct] = e;
          sum += e;
        }
        #pragma unroll
        for (int off = 1; off < 16; off <<= 1) sum += __shfl_xor(sum, off);
        float inv = 1.0f / sum;
        #pragma unroll
        for (int ct = 0; ct < 13; ++ct) {
          int gc = ct * 16 + lm;
          float p = sv[ct] * inv + ((gc == grow) ? 1.0f : 0.0f);   // P += I
          uint32 pb = bfb(p);
          uint32 qb = (uint32)__shfl_xor((int)pb, 1);
          if (!(lane & 1)) pl[grow * PLSTR + ct * 8 + (lm >> 1)] = pb | (qb << 16);
        }
      }
      // zero P cols 200..223 (dw 100..111) for this row-block
      for (int i = lane; i < 256; i += 64) {
        int rr = i >> 4, c = i & 15;
        if (c < 12) pl[(rb * 16 + rr) * PLSTR + 100 + c] = 0u;
      }
    }
  }

  // A-fragments (own rows only; this wave wrote them -> intra-wave, no barrier)
  bf16x8 pa[2][7];
  #pragma unroll
  for (int ks = 0; ks < 7; ++ks) {
    pa[0][ks] = *(const bf16x8*)&pl[(rb0 * 16 + lm) * PLSTR + ks * 16 + lg * 4];
    if (two)
      pa[1][ks] = *(const bf16x8*)&pl[(rb1 * 16 + lm) * PLSTR + ks * 16 + lg * 4];
  }

  // ---------------- Phase 2: out = (P+I) @ Xb (round-10 verbatim) ------------
  float pv[7][4];
  const int swz = ((lane >> 3) & 3) << 1;
  #pragma unroll
  for (int p = 0; p < 7; ++p) {        // preload chunk 0
    int rb4 = (p * 8 + w) * 4;
    #pragma unroll
    for (int q = 0; q < 4; ++q) {
      int r = rb4 + q;
      pv[p][q] = (r < CC) ? xb[r * LL + lane] : 0.f;
    }
  }
  #pragma unroll
  for (int p = 0; p < 7; ++p) {        // write chunk 0 -> xbf0 (xa0 dead: last
    int kpp = p * 8 + w;               //  slab read was xa1, barriers passed)
    uint2 wv;
    wv.x = bfb(pv[p][0]) | (bfb(pv[p][1]) << 16);
    wv.y = bfb(pv[p][2]) | (bfb(pv[p][3]) << 16);
    *(uint2*)&xbf0[lane * TSTR + 2 * (kpp ^ swz)] = wv;
  }

  for (int nc = 0; nc < 16; ++nc) {
    const int n0 = nc * 64;
    __syncthreads();                   // chunk nc staged by all; nc-2 reads done
    if (nc + 1 < 16) {                 // issue next chunk's loads (hide under MFMA)
      const int n1 = n0 + 64;
      #pragma unroll
      for (int p = 0; p < 7; ++p) {
        int rb4 = (p * 8 + w) * 4;
        #pragma unroll
        for (int q = 0; q < 4; ++q) {
          int r = rb4 + q;
          pv[p][q] = (r < CC) ? xb[r * LL + n1 + lane] : 0.f;
        }
      }
    }

    const uint32* XC = (nc & 1) ? xbf1 : xbf0;
    f32x4 acc2[2][4];
    #pragma unroll
    for (int i = 0; i < 2; ++i)
      #pragma unroll
      for (int j = 0; j < 4; ++j) acc2[i][j] = fz;

    __builtin_amdgcn_s_setprio(1);
    #pragma unroll
    for (int ks = 0; ks < 7; ++ks) {   // K = 224 (P cols 200..223 zero)
      #pragma unroll
      for (int ct = 0; ct < 4; ++ct) {
        int col = ct * 16 + lm;
        int s2 = ((col >> 3) & 3) << 1;
        bf16x8 b = *(const bf16x8*)&XC[col * TSTR + 2 * ((ks * 8 + lg * 2) ^ s2)];
        acc2[0][ct] = __builtin_amdgcn_mfma_f32_16x16x32_bf16(pa[0][ks], b, acc2[0][ct], 0, 0, 0);
        if (two)
          acc2[1][ct] = __builtin_amdgcn_mfma_f32_16x16x32_bf16(pa[1][ks], b, acc2[1][ct], 0, 0, 0);
      }
    }
    __builtin_amdgcn_s_setprio(0);

    if (nc + 1 < 16) {                 // write staged regs -> other buffer
      uint32* XN = (nc & 1) ? xbf0 : xbf1;
      #pragma unroll
      for (int p = 0; p < 7; ++p) {
        int kpp = p * 8 + w;
        uint2 wv;
        wv.x = bfb(pv[p][0]) | (bfb(pv[p][1]) << 16);
        wv.y = bfb(pv[p][2]) | (bfb(pv[p][3]) << 16);
        *(uint2*)&XN[lane * TSTR + 2 * (kpp ^ swz)] = wv;
      }
    }

    #pragma unroll
    for (int rbi = 0; rbi < 2; ++rbi) {
      if (rbi == 0 || two) {
        int rb = rbi ? rb1 : rb0;
        #pragma unroll
        for (int ct = 0; ct < 4; ++ct) {
          #pragma unroll
          for (int r = 0; r < 4; ++r) {
            int grow = rb * 16 + lg * 4 + r;
            if (grow < CC) ob[grow * LL + n0 + ct * 16 + lm] = acc2[rbi][ct][r];
          }
        }
      }
    }
  }
}

extern "C" void kernel_launch(void* const* d_in, const int* in_sizes, int n_in,
                              void* d_out, int out_size, void* d_ws, size_t ws_size,
                              hipStream_t stream) {
  const float* x = (const float*)d_in[0];
  float* out = (float*)d_out;
  const int B = in_sizes[0] / (CC * LL);   // 256
  spe_attn_kernel<<<dim3(B), dim3(512), 0, stream>>>(x, out);
}

// Round 13
// 140.310 us; speedup vs baseline: 2.4448x; 1.1140x over previous
//
#include <hip/hip_runtime.h>
#include <math.h>

// spe_self_atten: out[b] = softmax( (Xb Xb^T) / max(n_i n_j, eps) ) Xb + Xb
// B=256, C=200, L=1024. f32 in/out, bf16 MFMA internally. Residual via P += I.
// Round 13: round-10 base (151us, 3x verified) + ONE isolated change: phase-2
// chunk barriers become lgkmcnt-only (raw s_barrier). __syncthreads drains
// vmcnt(0), forcing each chunk's 51KB output-store stream to retire before any
// wave proceeds -- 16 serialized HBM-write drains per block with 1 block/CU.
// lgkm-only barriers keep LDS ping-pong correctness (r11-verified topology)
// while stores drain only at kernel end, overlapped with compute.

typedef unsigned int uint32;
typedef __attribute__((ext_vector_type(8))) short bf16x8;   // 8 bf16 (4 VGPRs)
typedef __attribute__((ext_vector_type(4))) float f32x4;    // MFMA accum

#define CC 200
#define LL 1024
#define EPSV 1e-8f
#define PLSTR 116   // P row stride (dw)
#define XASTR 36    // phase-1 slab row stride (dw), == 4 mod 32
#define TSTR 116    // phase-2 chunk col stride (dw)

__device__ __forceinline__ uint32 bfb(float f) {
  // f32 -> bf16 bits, round-to-nearest-even
  uint32 u = __float_as_uint(f);
  u += 0x7fffu + ((u >> 16) & 1u);
  return u >> 16;
}

// LDS-only barrier: drain LDS ops (producer writes visible to all waves after
// the barrier), raw s_barrier, compiler fences. Global loads AND STORES stay
// in flight -- __syncthreads would force s_waitcnt vmcnt(0) (the store drain).
__device__ __forceinline__ void barrier_lds() {
  asm volatile("s_waitcnt lgkmcnt(0)" ::: "memory");
  __builtin_amdgcn_s_barrier();
  asm volatile("" ::: "memory");
}

__global__ __launch_bounds__(512, 1)
void spe_attn_kernel(const float* __restrict__ x, float* __restrict__ out) {
  const int tid  = threadIdx.x;
  const int lane = tid & 63;
  const int w    = tid >> 6;       // wave 0..7
  const int lm   = lane & 15;
  const int lg   = lane >> 4;
  const int bidx = blockIdx.x;
  const float* xb = x + (size_t)bidx * (CC * LL);
  float* ob       = out + (size_t)bidx * (CC * LL);

  // LDS layout (dwords), total 39312 dw = 157,248 B:
  //  pl    [0,24128)      : P bf16, 208 rows x 232 cols (116 dw stride)
  //  xa0   [24128,31616)  : phase-1 slab buf A, 208 rows x 72 bf16 (36 dw)
  //  xa1   [31616,39104)  : phase-1 slab buf B
  //  xbf0/1 (alias xa0/xa1): phase-2 ping-pong chunk, col-major 64 x 116 dw
  //  norms [39104,39312)  : 208 floats
  __shared__ uint32 LDS[39312];
  uint32* pl    = LDS;
  uint32* xa0   = LDS + 24128;
  uint32* xa1   = LDS + 31616;
  uint32* xbf0  = LDS + 24128;
  uint32* xbf1  = LDS + 31616;
  float*  norms = (float*)(LDS + 39104);

  const bool two = (w < 5);            // waves 0..4 own row-tiles {w, w+8}
  const int rb0 = w;
  const int rb1 = two ? (w + 8) : w;

  // ---------------- Phase 1: Gram S = Xb Xb^T (round-10 verbatim) ------------
  const f32x4 fz = {0.f, 0.f, 0.f, 0.f};
  f32x4 acc[2][13];
  #pragma unroll
  for (int i = 0; i < 2; ++i)
    #pragma unroll
    for (int j = 0; j < 13; ++j) acc[i][j] = fz;

  // zero pad rows 200..207 of both slab buffers
  if (tid < 288) { xa0[7200 + tid] = 0u; xa1[7200 + tid] = 0u; }

  float4 vst[7];
  #pragma unroll
  for (int i = 0; i < 7; ++i) {       // stage slab 0 (k=0..63)
    int idx = tid + i * 512;
    if (idx < 3200) {
      int row = idx >> 4, c4 = idx & 15;
      vst[i] = *(const float4*)(xb + row * LL + c4 * 4);
    }
  }
  #pragma unroll
  for (int i = 0; i < 7; ++i) {
    int idx = tid + i * 512;
    if (idx < 3200) {
      int row = idx >> 4, c4 = idx & 15;
      uint2 wv;
      wv.x = bfb(vst[i].x) | (bfb(vst[i].y) << 16);
      wv.y = bfb(vst[i].z) | (bfb(vst[i].w) << 16);
      *(uint2*)&xa0[row * XASTR + c4 * 2] = wv;
    }
  }

  for (int s = 0; s < 16; ++s) {
    __syncthreads();                   // slab s visible
    if (s + 1 < 16) {                  // issue next-slab loads early
      #pragma unroll
      for (int i = 0; i < 7; ++i) {
        int idx = tid + i * 512;
        if (idx < 3200) {
          int row = idx >> 4, c4 = idx & 15;
          vst[i] = *(const float4*)(xb + row * LL + (s + 1) * 64 + c4 * 4);
        }
      }
    }
    const uint32* cur = (s & 1) ? xa1 : xa0;
    __builtin_amdgcn_s_setprio(1);
    #pragma unroll
    for (int ks = 0; ks < 2; ++ks) {
      bf16x8 a0 = *(const bf16x8*)&cur[(rb0 * 16 + lm) * XASTR + ks * 16 + lg * 4];
      bf16x8 a1 = a0;
      if (two) a1 = *(const bf16x8*)&cur[(rb1 * 16 + lm) * XASTR + ks * 16 + lg * 4];
      #pragma unroll
      for (int ct = 0; ct < 13; ++ct) {
        bf16x8 bf = *(const bf16x8*)&cur[(ct * 16 + lm) * XASTR + ks * 16 + lg * 4];
        acc[0][ct] = __builtin_amdgcn_mfma_f32_16x16x32_bf16(a0, bf, acc[0][ct], 0, 0, 0);
        if (two)
          acc[1][ct] = __builtin_amdgcn_mfma_f32_16x16x32_bf16(a1, bf, acc[1][ct], 0, 0, 0);
      }
    }
    __builtin_amdgcn_s_setprio(0);
    if (s + 1 < 16) {                  // write staged regs -> other buffer
      uint32* nxt = (s & 1) ? xa0 : xa1;
      #pragma unroll
      for (int i = 0; i < 7; ++i) {
        int idx = tid + i * 512;
        if (idx < 3200) {
          int row = idx >> 4, c4 = idx & 15;
          uint2 wv;
          wv.x = bfb(vst[i].x) | (bfb(vst[i].y) << 16);
          wv.y = bfb(vst[i].z) | (bfb(vst[i].w) << 16);
          *(uint2*)&nxt[row * XASTR + c4 * 2] = wv;
        }
      }
    }
  }

  // ---------------- norms from Gram diagonal (round-10 verbatim) -------------
  #pragma unroll
  for (int rbi = 0; rbi < 2; ++rbi) {
    if (rbi == 0 || two) {
      int rb = rbi ? rb1 : rb0;
      #pragma unroll
      for (int ct = 0; ct < 13; ++ct) {
        if (ct == rb) {
          #pragma unroll
          for (int r = 0; r < 4; ++r) {
            int ri = lg * 4 + r;
            if (lm == ri) norms[rb * 16 + ri] = sqrtf(acc[rbi][ct][r]);
          }
        }
      }
    }
  }
  __syncthreads();

  // ---------------- softmax rows + (P+I) -> LDS bf16 (round-10 verbatim) -----
  float cn[13];
  #pragma unroll
  for (int ct = 0; ct < 13; ++ct) cn[ct] = norms[ct * 16 + lm];

  #pragma unroll
  for (int rbi = 0; rbi < 2; ++rbi) {
    if (rbi == 0 || two) {
      int rb = rbi ? rb1 : rb0;
      #pragma unroll
      for (int r = 0; r < 4; ++r) {
        int grow = rb * 16 + lg * 4 + r;
        float rn = norms[grow];
        float sv[13];
        float m = -INFINITY;
        #pragma unroll
        for (int ct = 0; ct < 13; ++ct) {
          int gc = ct * 16 + lm;
          float sval = acc[rbi][ct][r] / fmaxf(rn * cn[ct], EPSV);
          sval = (gc < CC) ? sval : -INFINITY;
          sv[ct] = sval;
          m = fmaxf(m, sval);
        }
        #pragma unroll
        for (int off = 1; off < 16; off <<= 1) m = fmaxf(m, __shfl_xor(m, off));
        float sum = 0.f;
        #pragma unroll
        for (int ct = 0; ct < 13; ++ct) {
          float e = __expf(sv[ct] - m);
          sv[ct] = e;
          sum += e;
        }
        #pragma unroll
        for (int off = 1; off < 16; off <<= 1) sum += __shfl_xor(sum, off);
        float inv = 1.0f / sum;
        #pragma unroll
        for (int ct = 0; ct < 13; ++ct) {
          int gc = ct * 16 + lm;
          float p = sv[ct] * inv + ((gc == grow) ? 1.0f : 0.0f);   // P += I
          uint32 pb = bfb(p);
          uint32 qb = (uint32)__shfl_xor((int)pb, 1);
          if (!(lane & 1)) pl[grow * PLSTR + ct * 8 + (lm >> 1)] = pb | (qb << 16);
        }
      }
      // zero P cols 200..223 (dw 100..111) for this row-block
      for (int i = lane; i < 256; i += 64) {
        int rr = i >> 4, c = i & 15;
        if (c < 12) pl[(rb * 16 + rr) * PLSTR + 100 + c] = 0u;
      }
    }
  }

  // A-fragments (own rows only; this wave wrote them -> intra-wave, no barrier)
  bf16x8 pa[2][7];
  #pragma unroll
  for (int ks = 0; ks < 7; ++ks) {
    pa[0][ks] = *(const bf16x8*)&pl[(rb0 * 16 + lm) * PLSTR + ks * 16 + lg * 4];
    if (two)
      pa[1][ks] = *(const bf16x8*)&pl[(rb1 * 16 + lm) * PLSTR + ks * 16 + lg * 4];
  }

  // ---------------- Phase 2: out = (P+I) @ Xb, 16 chunks of 64 cols ----------
  // Round-10 mechanics; ONLY the barrier type changed to lgkm-only so the
  // 51KB/chunk output-store stream never force-drains inside the loop.
  float pv[7][4];
  const int swz = ((lane >> 3) & 3) << 1;
  #pragma unroll
  for (int p = 0; p < 7; ++p) {        // preload chunk 0
    int rb4 = (p * 8 + w) * 4;
    #pragma unroll
    for (int q = 0; q < 4; ++q) {
      int r = rb4 + q;
      pv[p][q] = (r < CC) ? xb[r * LL + lane] : 0.f;
    }
  }
  #pragma unroll
  for (int p = 0; p < 7; ++p) {        // write chunk 0 -> xbf0 (xa0 is dead:
    int kpp = p * 8 + w;               //  last slab read was xa1, barrier passed)
    uint2 wv;
    wv.x = bfb(pv[p][0]) | (bfb(pv[p][1]) << 16);
    wv.y = bfb(pv[p][2]) | (bfb(pv[p][3]) << 16);
    *(uint2*)&xbf0[lane * TSTR + 2 * (kpp ^ swz)] = wv;
  }

  for (int nc = 0; nc < 16; ++nc) {
    const int n0 = nc * 64;
    barrier_lds();                     // chunk nc staged (lgkm drained); global
                                       // loads/stores stay in flight
    if (nc + 1 < 16) {                 // issue next chunk's loads (hide under MFMA)
      const int n1 = n0 + 64;
      #pragma unroll
      for (int p = 0; p < 7; ++p) {
        int rb4 = (p * 8 + w) * 4;
        #pragma unroll
        for (int q = 0; q < 4; ++q) {
          int r = rb4 + q;
          pv[p][q] = (r < CC) ? xb[r * LL + n1 + lane] : 0.f;
        }
      }
    }

    const uint32* XC = (nc & 1) ? xbf1 : xbf0;
    f32x4 acc2[2][4];
    #pragma unroll
    for (int i = 0; i < 2; ++i)
      #pragma unroll
      for (int j = 0; j < 4; ++j) acc2[i][j] = fz;

    __builtin_amdgcn_s_setprio(1);
    #pragma unroll
    for (int ks = 0; ks < 7; ++ks) {   // K = 224 (P cols 200..223 zero)
      #pragma unroll
      for (int ct = 0; ct < 4; ++ct) {
        int col = ct * 16 + lm;
        int s2 = ((col >> 3) & 3) << 1;
        bf16x8 b = *(const bf16x8*)&XC[col * TSTR + 2 * ((ks * 8 + lg * 2) ^ s2)];
        acc2[0][ct] = __builtin_amdgcn_mfma_f32_16x16x32_bf16(pa[0][ks], b, acc2[0][ct], 0, 0, 0);
        if (two)
          acc2[1][ct] = __builtin_amdgcn_mfma_f32_16x16x32_bf16(pa[1][ks], b, acc2[1][ct], 0, 0, 0);
      }
    }
    __builtin_amdgcn_s_setprio(0);

    if (nc + 1 < 16) {                 // write staged regs -> other buffer
      uint32* XN = (nc & 1) ? xbf0 : xbf1;
      #pragma unroll
      for (int p = 0; p < 7; ++p) {
        int kpp = p * 8 + w;
        uint2 wv;
        wv.x = bfb(pv[p][0]) | (bfb(pv[p][1]) << 16);
        wv.y = bfb(pv[p][2]) | (bfb(pv[p][3]) << 16);
        *(uint2*)&XN[lane * TSTR + 2 * (kpp ^ swz)] = wv;
      }
    }

    #pragma unroll
    for (int rbi = 0; rbi < 2; ++rbi) {
      if (rbi == 0 || two) {
        int rb = rbi ? rb1 : rb0;
        #pragma unroll
        for (int ct = 0; ct < 4; ++ct) {
          #pragma unroll
          for (int r = 0; r < 4; ++r) {
            int grow = rb * 16 + lg * 4 + r;
            if (grow < CC) ob[grow * LL + n0 + ct * 16 + lm] = acc2[rbi][ct][r];
          }
        }
      }
    }
  }
}

extern "C" void kernel_launch(void* const* d_in, const int* in_sizes, int n_in,
                              void* d_out, int out_size, void* d_ws, size_t ws_size,
                              hipStream_t stream) {
  const float* x = (const float*)d_in[0];
  float* out = (float*)d_out;
  const int B = in_sizes[0] / (CC * LL);   // 256
  spe_attn_kernel<<<dim3(B), dim3(512), 0, stream>>>(x, out);
}